// Round 2
// baseline (601.594 us; speedup 1.0000x reference)
//
#include <hip/hip_runtime.h>
#include <hip/hip_bf16.h>

#define SNUM 1024
#define PNUM 60
#define KFPS 10
#define NMASK 800
#define WORDS 25        // 800/32
#define HWDIM 256
#define FD 512
#define NPTS (SNUM*PNUM)
#define EDGE_CAP (1u<<20)

__device__ __forceinline__ float fmul(float a, float b){ return __fmul_rn(a,b); }
__device__ __forceinline__ float fadd(float a, float b){ return __fadd_rn(a,b); }
__device__ __forceinline__ float fsub(float a, float b){ return __fsub_rn(a,b); }

// squared distance, jnp order: (dx*dx + dy*dy) + dz*dz, no fma contraction
__device__ __forceinline__ float dist2f(float ax,float ay,float az,float bx,float by,float bz){
    float dx=fsub(ax,bx), dy=fsub(ay,by), dz=fsub(az,bz);
    return fadd(fadd(fmul(dx,dx),fmul(dy,dy)),fmul(dz,dz));
}

// ---------------- 1. FPS reps (1 wave per superpoint) ----------------
__global__ __launch_bounds__(64) void k_fps(const float* __restrict__ pcds,
                                            float* __restrict__ reps){
    int s = blockIdx.x;
    int l = threadIdx.x;
    float x=0.f,y=0.f,z=0.f;
    if (l < PNUM){
        const float* p = pcds + (size_t)(s*PNUM + l)*3;
        x=p[0]; y=p[1]; z=p[2];
    }
    float x0=__shfl(x,0), y0=__shfl(y,0), z0=__shfl(z,0);
    float dist = dist2f(x,y,z,x0,y0,z0);
    int sel[KFPS];
    sel[0]=0;
    #pragma unroll
    for(int it=1; it<KFPS; ++it){
        float v = (l<PNUM)? dist : -INFINITY;
        int idx = l;
        #pragma unroll
        for(int off=32; off; off>>=1){
            float ov = __shfl_xor(v, off);
            int   oi = __shfl_xor(idx, off);
            if (ov > v || (ov==v && oi<idx)){ v=ov; idx=oi; }
        }
        sel[it]=idx;
        float sx=__shfl(x,idx), sy=__shfl(y,idx), sz=__shfl(z,idx);
        float nd = dist2f(x,y,z,sx,sy,sz);
        dist = fminf(dist, nd);
    }
    #pragma unroll
    for(int j=0;j<KFPS;++j){
        float rx=__shfl(x,sel[j]), ry=__shfl(y,sel[j]), rz=__shfl(z,sel[j]);
        if (l==0){
            float* o = reps + (size_t)(s*KFPS+j)*3;
            o[0]=rx; o[1]=ry; o[2]=rz;
        }
    }
}

// ---------------- 2. per-point pixel index (-1 if not visible) ----------------
__global__ void k_pix(const int* __restrict__ mapping, int* __restrict__ pix){
    int p = blockIdx.x*blockDim.x + threadIdx.x;
    if (p >= NPTS) return;
    int y = mapping[p*4+1], x = mapping[p*4+2], v = mapping[p*4+3];
    y = min(max(y,0),HWDIM-1); x = min(max(x,0),HWDIM-1);
    pix[p] = (v==1) ? (y*HWDIM + x) : -1;
}

// ---------------- 2b. detect mask dtype (uint8 bool vs int32) ----------------
__global__ void k_detect(const unsigned char* __restrict__ m8, unsigned int* __restrict__ flag){
    int t = blockIdx.x*blockDim.x + threadIdx.x;
    for (int i = t; i < 65536; i += blockDim.x*gridDim.x){
        if ((i & 3) != 0 && m8[i] == 1) atomicOr(flag, 1u);
    }
}

// ---------------- 3. pack masks to pixel-major bitwords ----------------
__global__ void k_pack(const unsigned char* __restrict__ m8,
                       const int* __restrict__ m32,
                       const unsigned int* __restrict__ flag,
                       unsigned int* __restrict__ pb){
    int g = blockIdx.x*blockDim.x + threadIdx.x;   // [0, 65536*25)
    if (g >= HWDIM*HWDIM*WORDS) return;
    int w = g >> 16;
    int pixel = g & 0xFFFF;
    unsigned int word = 0;
    if (*flag){ // uint8 bool layout
        const unsigned char* base = m8 + (size_t)(w*32)*65536 + pixel;
        #pragma unroll
        for (int b=0;b<32;++b)
            word |= (unsigned int)(base[(size_t)b*65536] & 1u) << b;
    } else {    // int32 layout
        const int* base = m32 + (size_t)(w*32)*65536 + pixel;
        #pragma unroll
        for (int b=0;b<32;++b)
            word |= (unsigned int)(base[(size_t)b*65536] & 1) << b;
    }
    pb[pixel*WORDS + w] = word;
}

// ---------------- 4. coverage counts per (superpoint, mask) ----------------
__global__ void k_cov(const int* __restrict__ pix, const unsigned int* __restrict__ pb,
                      unsigned char* __restrict__ cntT){
    int t = blockIdx.x*blockDim.x + threadIdx.x;
    if (t >= SNUM*WORDS) return;
    int s = t / WORDS, w = t % WORDS;
    int acc[32];
    #pragma unroll
    for(int b=0;b<32;++b) acc[b]=0;
    for(int p=0;p<PNUM;++p){
        int px = pix[s*PNUM+p];
        if (px >= 0){
            unsigned int word = pb[(size_t)px*WORDS + w];
            #pragma unroll
            for(int b=0;b<32;++b) acc[b] += (word>>b)&1u;
        }
    }
    #pragma unroll
    for(int b=0;b<32;++b)
        cntT[(size_t)(w*32+b)*SNUM + s] = (unsigned char)acc[b];
}

// ---------------- 5. stable top-10 per mask + contrib bits + conf sums ----------------
__global__ __launch_bounds__(256) void k_topk(const unsigned char* __restrict__ cntT,
                                              const float* __restrict__ scores,
                                              unsigned int* __restrict__ contrib,
                                              float* __restrict__ wsum,
                                              float* __restrict__ fsum){
    int m = blockIdx.x;
    int t = threadIdx.x;
    __shared__ int hist[64];
    __shared__ int scan_s[256];
    __shared__ int sT, sR;
    if (t < 64) hist[t]=0;
    __syncthreads();
    uchar4 c4 = ((const uchar4*)(cntT + (size_t)m*SNUM))[t];
    int c[4] = {(int)c4.x,(int)c4.y,(int)c4.z,(int)c4.w};
    atomicAdd(&hist[c[0]],1); atomicAdd(&hist[c[1]],1);
    atomicAdd(&hist[c[2]],1); atomicAdd(&hist[c[3]],1);
    __syncthreads();
    if (t==0){
        int running=0, T=0, r=10;
        for(int v=63;v>=0;--v){
            int nr = running + hist[v];
            if (nr >= 10){ T=v; r=10-running; break; }
            running = nr;
        }
        sT=T; sR=r;
    }
    __syncthreads();
    int T=sT, r=sR;
    int eq = (c[0]==T)+(c[1]==T)+(c[2]==T)+(c[3]==T);
    scan_s[t]=eq; __syncthreads();
    for(int off=1;off<256;off<<=1){
        int v = (t>=off)? scan_s[t-off] : 0;
        __syncthreads();
        scan_s[t]+=v;
        __syncthreads();
    }
    int rank = scan_s[t]-eq;   // exclusive prefix of (cnt==T) by index
    float sc = scores[m];
    #pragma unroll
    for(int j=0;j<4;++j){
        int s = t*4+j;
        bool selv = (c[j]>T) || (c[j]==T && rank<r);
        if (c[j]==T) rank++;
        if (selv && c[j]>0){
            float frac = (float)c[j]/60.0f;
            atomicAdd(&wsum[s], frac*sc);
            atomicAdd(&fsum[s], frac);
            if (c[j] >= 12)
                atomicOr(&contrib[s*WORDS + (m>>5)], 1u<<(m&31));
        }
    }
}

// ---------------- 6. adj0 + edge list ----------------
__global__ __launch_bounds__(256) void k_adj0(const float* __restrict__ reps,
                                              float* __restrict__ out,
                                              unsigned int* __restrict__ ecnt,
                                              unsigned int* __restrict__ edges){
    __shared__ float ri[16][KFPS][3], rj[16][KFPS][3];
    __shared__ float sqi[16][KFPS], sqj[16][KFPS];
    int tx = threadIdx.x, ty = threadIdx.y;
    int i0 = blockIdx.y*16, j0 = blockIdx.x*16;
    int t = ty*16+tx;
    for(int u=t; u<16*KFPS*3; u+=256){
        ((float*)ri)[u] = reps[(size_t)i0*KFPS*3 + u];
        ((float*)rj)[u] = reps[(size_t)j0*KFPS*3 + u];
    }
    __syncthreads();
    if (t < 16*KFPS){
        int sp=t/KFPS, k=t%KFPS;
        float x=ri[sp][k][0], y=ri[sp][k][1], z=ri[sp][k][2];
        sqi[sp][k]=fadd(fadd(fmul(x,x),fmul(y,y)),fmul(z,z));
        x=rj[sp][k][0]; y=rj[sp][k][1]; z=rj[sp][k][2];
        sqj[sp][k]=fadd(fadd(fmul(x,x),fmul(y,y)),fmul(z,z));
    }
    __syncthreads();
    int i = i0+ty, j = j0+tx;
    float m2 = INFINITY;
    #pragma unroll 2
    for(int k=0;k<KFPS;++k){
        float ax=ri[ty][k][0], ay=ri[ty][k][1], az=ri[ty][k][2], as=sqi[ty][k];
        #pragma unroll
        for(int l=0;l<KFPS;++l){
            float dot = fadd(fadd(fmul(ax,rj[tx][l][0]),fmul(ay,rj[tx][l][1])),fmul(az,rj[tx][l][2]));
            float d2 = fmaxf(fsub(fadd(as,sqj[tx][l]), fmul(2.0f,dot)), 0.0f);
            m2 = fminf(m2,d2);
        }
    }
    float d = sqrtf(fadd(m2,1e-12f));
    bool edge = (d < 0.2f) && (i!=j);
    out[(size_t)i*SNUM + j] = edge ? expf(-d) : 0.0f;
    if (edge){
        unsigned int e = atomicAdd(ecnt, 1u);
        if (e < EDGE_CAP) edges[e] = ((unsigned int)i<<10) | (unsigned int)j;
    }
}

// ---------------- 7. normalized mean features ----------------
__global__ __launch_bounds__(256) void k_feats(const float* __restrict__ pf,
                                               float* __restrict__ feats){
    int s = blockIdx.x, t = threadIdx.x;
    float a0=0.f, a1=0.f;
    const float* base = pf + (size_t)s*PNUM*FD;
    for(int p=0;p<PNUM;++p){
        a0 += base[(size_t)p*FD + t];
        a1 += base[(size_t)p*FD + t + 256];
    }
    a0 /= 60.0f; a1 /= 60.0f;
    __shared__ float red[256];
    red[t]=a0*a0 + a1*a1; __syncthreads();
    for(int off=128;off;off>>=1){ if(t<off) red[t]+=red[t+off]; __syncthreads(); }
    float denom = fmaxf(sqrtf(red[0]), 1e-12f);
    feats[(size_t)s*FD + t]       = a0/denom;
    feats[(size_t)s*FD + t + 256] = a1/denom;
}

// ---------------- 8. mod per edge, fold into adjacency ----------------
__global__ __launch_bounds__(64) void k_mod(const unsigned int* __restrict__ ecnt,
                                            const unsigned int* __restrict__ edges,
                                            const unsigned int* __restrict__ contrib,
                                            const float* __restrict__ feats,
                                            float* __restrict__ out){
    unsigned int n = *ecnt; if (n > EDGE_CAP) n = EDGE_CAP;
    int lane = threadIdx.x;
    for (unsigned int e = blockIdx.x; e < n; e += gridDim.x){
        unsigned int pk = edges[e];
        int i = (int)(pk>>10), j = (int)(pk & 1023u);
        const float4* fi = (const float4*)(feats + (size_t)i*FD);
        const float4* fj = (const float4*)(feats + (size_t)j*FD);
        float dot = 0.f;
        #pragma unroll
        for(int r=0;r<2;++r){
            float4 a = fi[lane + 64*r], b = fj[lane + 64*r];
            dot += a.x*b.x + a.y*b.y + a.z*b.z + a.w*b.w;
        }
        #pragma unroll
        for(int off=32;off;off>>=1) dot += __shfl_xor(dot,off);

        unsigned int u=0, aw=0; int cw=0;
        if (lane < WORDS){
            unsigned int bi = contrib[i*WORDS+lane], bj = contrib[j*WORDS+lane];
            u = bi|bj; aw = bi&bj; cw = __popc(u);
        }
        int pre=0, ctot=0;
        for(int k2=0;k2<WORDS;++k2){
            int v=__shfl(cw,k2);
            ctot += v;
            if (k2<lane) pre += v;
        }
        int il=0;
        if (lane<WORDS && pre<5){
            unsigned int x=u;
            int lim = 5-pre;
            #pragma unroll
            for(int q=0;q<5;++q){
                if (q<lim && x){
                    int b = __ffs(x)-1;
                    il += (int)((aw>>b)&1u);
                    x &= x-1;
                }
            }
        }
        #pragma unroll
        for(int off=32;off;off>>=1) il += __shfl_xor(il,off);
        int uni = min(ctot,5);
        float ov = (float)il / ((float)uni + 1e-6f);
        float sim = fminf(fmaxf((dot+1.0f)*0.5f,0.0f),1.0f);
        if (sim < 0.5f) sim = 1.0f;
        float mod = ov*sim;
        if (lane==0){
            size_t o = (size_t)i*SNUM+j;
            out[o] = fmaxf(out[o], mod);
        }
    }
}

// ---------------- 9. confidence ----------------
__global__ void k_conf(const float* __restrict__ wsum, const float* __restrict__ fsum,
                       float* __restrict__ conf){
    int s = blockIdx.x*blockDim.x+threadIdx.x;
    if (s>=SNUM) return;
    conf[s] = fmaxf(wsum[s]/(fsum[s]+1e-6f), 0.0f);
}

extern "C" void kernel_launch(void* const* d_in, const int* in_sizes, int n_in,
                              void* d_out, int out_size, void* d_ws, size_t ws_size,
                              hipStream_t stream){
    const float*         pcds    = (const float*)d_in[0];
    const unsigned char* masks8  = (const unsigned char*)d_in[2];
    const int*           masks32 = (const int*)d_in[2];
    const int*           mapping = (const int*)d_in[3];
    const float*         scores  = (const float*)d_in[4];
    const float*         pf      = (const float*)d_in[5];
    float* out_adj  = (float*)d_out;
    float* out_conf = out_adj + (size_t)SNUM*SNUM;

    char* ws = (char*)d_ws;
    float*         reps    = (float*)(ws + 0);               // 122880 B
    int*           pix     = (int*)(ws + 122880);            // 245760 B
    unsigned int*  pb      = (unsigned int*)(ws + 368640);   // 6553600 B
    unsigned char* cntT    = (unsigned char*)(ws + 6922240); // 819200 B
    unsigned int*  contrib = (unsigned int*)(ws + 7741440);  // 102400 B (zeroed)
    float*         wsum    = (float*)(ws + 7843840);         // 4096 B (zeroed)
    float*         fsum    = (float*)(ws + 7847936);         // 4096 B (zeroed)
    unsigned int*  ecnt    = (unsigned int*)(ws + 7852032);  // 4 B (zeroed)
    unsigned int*  dflag   = (unsigned int*)(ws + 7852036);  // 4 B (zeroed)
    unsigned int*  edges   = (unsigned int*)(ws + 7852288);  // 4 MB (cap 1M edges)
    float*         feats   = (float*)(ws + 12046592);        // 2 MB; total ~13.5 MB

    hipMemsetAsync(ws + 7741440, 0, 110848, stream);

    k_detect<<<1, 256, 0, stream>>>(masks8, dflag);
    k_fps   <<<SNUM, 64, 0, stream>>>(pcds, reps);
    k_pix   <<<(NPTS+255)/256, 256, 0, stream>>>(mapping, pix);
    k_pack  <<<(HWDIM*HWDIM*WORDS+255)/256, 256, 0, stream>>>(masks8, masks32, dflag, pb);
    k_cov   <<<(SNUM*WORDS+255)/256, 256, 0, stream>>>(pix, pb, cntT);
    k_topk  <<<NMASK, 256, 0, stream>>>(cntT, scores, contrib, wsum, fsum);
    k_adj0  <<<dim3(64,64), dim3(16,16), 0, stream>>>(reps, out_adj, ecnt, edges);
    k_feats <<<SNUM, 256, 0, stream>>>(pf, feats);
    k_mod   <<<1024, 64, 0, stream>>>(ecnt, edges, contrib, feats, out_adj);
    k_conf  <<<(SNUM+255)/256, 256, 0, stream>>>(wsum, fsum, out_conf);
}

// Round 3
// 466.283 us; speedup vs baseline: 1.2902x; 1.2902x over previous
//
#include <hip/hip_runtime.h>
#include <hip/hip_bf16.h>

#define SNUM 1024
#define PNUM 60
#define KFPS 10
#define NMASK 800
#define WORDS 25        // 800/32
#define HWDIM 256
#define FD 512
#define NPTS (SNUM*PNUM)
#define EDGE_CAP (1u<<20)

__device__ __forceinline__ float fmul(float a, float b){ return __fmul_rn(a,b); }
__device__ __forceinline__ float fadd(float a, float b){ return __fadd_rn(a,b); }
__device__ __forceinline__ float fsub(float a, float b){ return __fsub_rn(a,b); }

// squared distance, jnp order: (dx*dx + dy*dy) + dz*dz, no fma contraction
__device__ __forceinline__ float dist2f(float ax,float ay,float az,float bx,float by,float bz){
    float dx=fsub(ax,bx), dy=fsub(ay,by), dz=fsub(az,bz);
    return fadd(fadd(fmul(dx,dx),fmul(dy,dy)),fmul(dz,dz));
}

// ---------------- 1. FPS reps (1 wave per superpoint) ----------------
__global__ __launch_bounds__(64) void k_fps(const float* __restrict__ pcds,
                                            float* __restrict__ reps){
    int s = blockIdx.x;
    int l = threadIdx.x;
    float x=0.f,y=0.f,z=0.f;
    if (l < PNUM){
        const float* p = pcds + (size_t)(s*PNUM + l)*3;
        x=p[0]; y=p[1]; z=p[2];
    }
    float x0=__shfl(x,0), y0=__shfl(y,0), z0=__shfl(z,0);
    float dist = dist2f(x,y,z,x0,y0,z0);
    int sel[KFPS];
    sel[0]=0;
    #pragma unroll
    for(int it=1; it<KFPS; ++it){
        float v = (l<PNUM)? dist : -INFINITY;
        int idx = l;
        #pragma unroll
        for(int off=32; off; off>>=1){
            float ov = __shfl_xor(v, off);
            int   oi = __shfl_xor(idx, off);
            if (ov > v || (ov==v && oi<idx)){ v=ov; idx=oi; }
        }
        sel[it]=idx;
        float sx=__shfl(x,idx), sy=__shfl(y,idx), sz=__shfl(z,idx);
        float nd = dist2f(x,y,z,sx,sy,sz);
        dist = fminf(dist, nd);
    }
    #pragma unroll
    for(int j=0;j<KFPS;++j){
        float rx=__shfl(x,sel[j]), ry=__shfl(y,sel[j]), rz=__shfl(z,sel[j]);
        if (l==0){
            float* o = reps + (size_t)(s*KFPS+j)*3;
            o[0]=rx; o[1]=ry; o[2]=rz;
        }
    }
}

// ---------------- 2. detect mask dtype (uint8 bool vs int32) ----------------
__global__ void k_detect(const unsigned char* __restrict__ m8, unsigned int* __restrict__ flag){
    int t = blockIdx.x*blockDim.x + threadIdx.x;
    for (int i = t; i < 65536; i += blockDim.x*gridDim.x){
        if ((i & 3) != 0 && m8[i] == 1) atomicOr(flag, 1u);
    }
}

// ---------------- 3. pack masks -> pixel-major bitwords (LDS-staged) ----------------
// tile = 256 pixels; thread t owns pixel pixBase+t; builds 25 words in LDS; coalesced uint4 out.
__global__ __launch_bounds__(256) void k_pack(const unsigned char* __restrict__ m8,
                                              const int* __restrict__ m32,
                                              const unsigned int* __restrict__ flag,
                                              unsigned int* __restrict__ pb){
    __shared__ unsigned int lds[256*WORDS];
    int t = threadIdx.x;
    int pixBase = blockIdx.x * 256;
    int pixel = pixBase + t;
    if (*flag){ // uint8 bool layout
        for (int w=0; w<WORDS; ++w){
            unsigned int word = 0;
            #pragma unroll
            for (int b=0;b<32;++b)
                word |= (unsigned int)(m8[(size_t)((w*32+b))*65536 + pixel] & 1u) << b;
            lds[t*WORDS + w] = word;
        }
    } else {    // int32 layout
        for (int w=0; w<WORDS; ++w){
            unsigned int word = 0;
            #pragma unroll
            for (int b=0;b<32;++b)
                word |= (unsigned int)(m32[(size_t)((w*32+b))*65536 + pixel] & 1) << b;
            lds[t*WORDS + w] = word;
        }
    }
    __syncthreads();
    // write 256*25 = 6400 words = 1600 uint4, contiguous
    uint4* out4 = (uint4*)(pb + (size_t)pixBase*WORDS);
    const uint4* l4 = (const uint4*)lds;
    for (int u=t; u<1600; u+=256) out4[u] = l4[u];
}

// ---------------- 4. coverage counts (pix fused, LDS-staged, byte-packed acc) ----------------
// block = 8 superpoints x 32 lanes (25 words active). grid 128.
__global__ __launch_bounds__(256) void k_cov(const int* __restrict__ mapping,
                                             const unsigned int* __restrict__ pb,
                                             unsigned char* __restrict__ cntT){
    __shared__ int pxl[8][PNUM];
    int t = threadIdx.x;
    int sBase = blockIdx.x * 8;
    for (int idx=t; idx<8*PNUM; idx+=256){
        int ls = idx / PNUM, p = idx - ls*PNUM;
        const int4 v = ((const int4*)mapping)[(sBase+ls)*PNUM + p];
        int y = min(max(v.y,0),HWDIM-1), x = min(max(v.z,0),HWDIM-1);
        pxl[ls][p] = (v.w==1) ? ((y<<8)|x) : -1;
    }
    __syncthreads();
    int ls = t >> 5, w = t & 31;
    if (w >= WORDS) return;
    unsigned int acc8[8];
    #pragma unroll
    for (int k=0;k<8;++k) acc8[k]=0;
    #pragma unroll 6
    for (int p=0;p<PNUM;++p){
        int px = pxl[ls][p];
        if (px >= 0){
            unsigned int word = pb[(size_t)px*WORDS + w];
            #pragma unroll
            for (int k=0;k<8;++k)
                acc8[k] += (word >> k) & 0x01010101u;
        }
    }
    int s = sBase + ls;
    #pragma unroll
    for (int k=0;k<8;++k)
        #pragma unroll
        for (int j=0;j<4;++j){
            int b = k + 8*j;
            cntT[(size_t)(w*32+b)*SNUM + s] = (unsigned char)((acc8[k] >> (8*j)) & 0xFF);
        }
}

// ---------------- 5. stable top-10 per mask + contrib bits + conf sums ----------------
__global__ __launch_bounds__(256) void k_topk(const unsigned char* __restrict__ cntT,
                                              const float* __restrict__ scores,
                                              unsigned int* __restrict__ contrib,
                                              float* __restrict__ wsum,
                                              float* __restrict__ fsum){
    int m = blockIdx.x;
    int t = threadIdx.x;
    __shared__ int hist[64];
    __shared__ int scan_s[256];
    __shared__ int sT, sR;
    if (t < 64) hist[t]=0;
    __syncthreads();
    uchar4 c4 = ((const uchar4*)(cntT + (size_t)m*SNUM))[t];
    int c[4] = {(int)c4.x,(int)c4.y,(int)c4.z,(int)c4.w};
    atomicAdd(&hist[c[0]],1); atomicAdd(&hist[c[1]],1);
    atomicAdd(&hist[c[2]],1); atomicAdd(&hist[c[3]],1);
    __syncthreads();
    if (t==0){
        int running=0, T=0, r=10;
        for(int v=63;v>=0;--v){
            int nr = running + hist[v];
            if (nr >= 10){ T=v; r=10-running; break; }
            running = nr;
        }
        sT=T; sR=r;
    }
    __syncthreads();
    int T=sT, r=sR;
    int eq = (c[0]==T)+(c[1]==T)+(c[2]==T)+(c[3]==T);
    scan_s[t]=eq; __syncthreads();
    for(int off=1;off<256;off<<=1){
        int v = (t>=off)? scan_s[t-off] : 0;
        __syncthreads();
        scan_s[t]+=v;
        __syncthreads();
    }
    int rank = scan_s[t]-eq;   // exclusive prefix of (cnt==T) by index
    float sc = scores[m];
    #pragma unroll
    for(int j=0;j<4;++j){
        int s = t*4+j;
        bool selv = (c[j]>T) || (c[j]==T && rank<r);
        if (c[j]==T) rank++;
        if (selv && c[j]>0){
            float frac = (float)c[j]/60.0f;
            atomicAdd(&wsum[s], frac*sc);
            atomicAdd(&fsum[s], frac);
            if (c[j] >= 12)
                atomicOr(&contrib[s*WORDS + (m>>5)], 1u<<(m&31));
        }
    }
}

// ---------------- 6. adj0 + edge list (+ fused confidence) ----------------
__global__ __launch_bounds__(256) void k_adj0(const float* __restrict__ reps,
                                              float* __restrict__ out,
                                              unsigned int* __restrict__ ecnt,
                                              unsigned int* __restrict__ edges,
                                              const float* __restrict__ wsum,
                                              const float* __restrict__ fsum,
                                              float* __restrict__ conf){
    __shared__ float ri[16][KFPS][3], rj[16][KFPS][3];
    __shared__ float sqi[16][KFPS], sqj[16][KFPS];
    int tx = threadIdx.x, ty = threadIdx.y;
    int t = ty*16+tx;
    if (blockIdx.y==0 && blockIdx.x<4){
        int s = blockIdx.x*256 + t;
        conf[s] = fmaxf(wsum[s]/(fsum[s]+1e-6f), 0.0f);
    }
    int i0 = blockIdx.y*16, j0 = blockIdx.x*16;
    for(int u=t; u<16*KFPS*3; u+=256){
        ((float*)ri)[u] = reps[(size_t)i0*KFPS*3 + u];
        ((float*)rj)[u] = reps[(size_t)j0*KFPS*3 + u];
    }
    __syncthreads();
    if (t < 16*KFPS){
        int sp=t/KFPS, k=t%KFPS;
        float x=ri[sp][k][0], y=ri[sp][k][1], z=ri[sp][k][2];
        sqi[sp][k]=fadd(fadd(fmul(x,x),fmul(y,y)),fmul(z,z));
        x=rj[sp][k][0]; y=rj[sp][k][1]; z=rj[sp][k][2];
        sqj[sp][k]=fadd(fadd(fmul(x,x),fmul(y,y)),fmul(z,z));
    }
    __syncthreads();
    int i = i0+ty, j = j0+tx;
    float m2 = INFINITY;
    #pragma unroll 2
    for(int k=0;k<KFPS;++k){
        float ax=ri[ty][k][0], ay=ri[ty][k][1], az=ri[ty][k][2], as=sqi[ty][k];
        #pragma unroll
        for(int l=0;l<KFPS;++l){
            float dot = fadd(fadd(fmul(ax,rj[tx][l][0]),fmul(ay,rj[tx][l][1])),fmul(az,rj[tx][l][2]));
            float d2 = fmaxf(fsub(fadd(as,sqj[tx][l]), fmul(2.0f,dot)), 0.0f);
            m2 = fminf(m2,d2);
        }
    }
    float d = sqrtf(fadd(m2,1e-12f));
    bool edge = (d < 0.2f) && (i!=j);
    out[(size_t)i*SNUM + j] = edge ? expf(-d) : 0.0f;
    if (edge){
        unsigned int e = atomicAdd(ecnt, 1u);
        if (e < EDGE_CAP) edges[e] = ((unsigned int)i<<10) | (unsigned int)j;
    }
}

// ---------------- 7. normalized mean features (float4, 2-way row split) ----------------
__global__ __launch_bounds__(256) void k_feats(const float* __restrict__ pf,
                                               float* __restrict__ feats){
    int s = blockIdx.x, t = threadIdx.x;
    int g = t >> 7;          // row group 0/1
    int c = t & 127;         // float4 column
    const float4* pf4 = (const float4*)pf;
    float4 a = make_float4(0.f,0.f,0.f,0.f);
    for (int p=g; p<PNUM; p+=2){
        float4 v = pf4[(size_t)(s*PNUM+p)*128 + c];
        a.x+=v.x; a.y+=v.y; a.z+=v.z; a.w+=v.w;
    }
    __shared__ float4 part[2][128];
    part[g][c] = a;
    __shared__ float red[256];
    __syncthreads();
    float4 m = make_float4(0.f,0.f,0.f,0.f);
    float ss = 0.f;
    if (g==0){
        float4 b = part[1][c];
        m.x=(a.x+b.x)/60.0f; m.y=(a.y+b.y)/60.0f; m.z=(a.z+b.z)/60.0f; m.w=(a.w+b.w)/60.0f;
        ss = m.x*m.x + m.y*m.y + m.z*m.z + m.w*m.w;
    }
    red[t] = ss; __syncthreads();
    for (int off=128; off; off>>=1){ if (t<off) red[t]+=red[t+off]; __syncthreads(); }
    float denom = fmaxf(sqrtf(red[0]), 1e-12f);
    if (g==0){
        float4 o; o.x=m.x/denom; o.y=m.y/denom; o.z=m.z/denom; o.w=m.w/denom;
        ((float4*)feats)[(size_t)s*128 + c] = o;
    }
}

// ---------------- 8. mod per edge, fold into adjacency ----------------
__global__ __launch_bounds__(64) void k_mod(const unsigned int* __restrict__ ecnt,
                                            const unsigned int* __restrict__ edges,
                                            const unsigned int* __restrict__ contrib,
                                            const float* __restrict__ feats,
                                            float* __restrict__ out){
    unsigned int n = *ecnt; if (n > EDGE_CAP) n = EDGE_CAP;
    int lane = threadIdx.x;
    for (unsigned int e = blockIdx.x; e < n; e += gridDim.x){
        unsigned int pk = edges[e];
        int i = (int)(pk>>10), j = (int)(pk & 1023u);
        const float4* fi = (const float4*)(feats + (size_t)i*FD);
        const float4* fj = (const float4*)(feats + (size_t)j*FD);
        float dot = 0.f;
        #pragma unroll
        for(int r=0;r<2;++r){
            float4 a = fi[lane + 64*r], b = fj[lane + 64*r];
            dot += a.x*b.x + a.y*b.y + a.z*b.z + a.w*b.w;
        }
        #pragma unroll
        for(int off=32;off;off>>=1) dot += __shfl_xor(dot,off);

        unsigned int u=0, aw=0; int cw=0;
        if (lane < WORDS){
            unsigned int bi = contrib[i*WORDS+lane], bj = contrib[j*WORDS+lane];
            u = bi|bj; aw = bi&bj; cw = __popc(u);
        }
        int pre=0, ctot=0;
        for(int k2=0;k2<WORDS;++k2){
            int v=__shfl(cw,k2);
            ctot += v;
            if (k2<lane) pre += v;
        }
        int il=0;
        if (lane<WORDS && pre<5){
            unsigned int x=u;
            int lim = 5-pre;
            #pragma unroll
            for(int q=0;q<5;++q){
                if (q<lim && x){
                    int b = __ffs(x)-1;
                    il += (int)((aw>>b)&1u);
                    x &= x-1;
                }
            }
        }
        #pragma unroll
        for(int off=32;off;off>>=1) il += __shfl_xor(il,off);
        int uni = min(ctot,5);
        float ov = (float)il / ((float)uni + 1e-6f);
        float sim = fminf(fmaxf((dot+1.0f)*0.5f,0.0f),1.0f);
        if (sim < 0.5f) sim = 1.0f;
        float mod = ov*sim;
        if (lane==0){
            size_t o = (size_t)i*SNUM+j;
            out[o] = fmaxf(out[o], mod);
        }
    }
}

extern "C" void kernel_launch(void* const* d_in, const int* in_sizes, int n_in,
                              void* d_out, int out_size, void* d_ws, size_t ws_size,
                              hipStream_t stream){
    const float*         pcds    = (const float*)d_in[0];
    const unsigned char* masks8  = (const unsigned char*)d_in[2];
    const int*           masks32 = (const int*)d_in[2];
    const int*           mapping = (const int*)d_in[3];
    const float*         scores  = (const float*)d_in[4];
    const float*         pf      = (const float*)d_in[5];
    float* out_adj  = (float*)d_out;
    float* out_conf = out_adj + (size_t)SNUM*SNUM;

    char* ws = (char*)d_ws;
    float*         reps    = (float*)(ws + 0);               // 122880 B
    unsigned int*  pb      = (unsigned int*)(ws + 368640);   // 6553600 B
    unsigned char* cntT    = (unsigned char*)(ws + 6922240); // 819200 B
    unsigned int*  contrib = (unsigned int*)(ws + 7741440);  // 102400 B (zeroed)
    float*         wsum    = (float*)(ws + 7843840);         // 4096 B (zeroed)
    float*         fsum    = (float*)(ws + 7847936);         // 4096 B (zeroed)
    unsigned int*  ecnt    = (unsigned int*)(ws + 7852032);  // 4 B (zeroed)
    unsigned int*  dflag   = (unsigned int*)(ws + 7852036);  // 4 B (zeroed)
    unsigned int*  edges   = (unsigned int*)(ws + 7852288);  // 4 MB (cap 1M edges)
    float*         feats   = (float*)(ws + 12046592);        // 2 MB; total ~13.5 MB

    hipMemsetAsync(ws + 7741440, 0, 110848, stream);

    k_detect<<<64, 256, 0, stream>>>(masks8, dflag);
    k_fps   <<<SNUM, 64, 0, stream>>>(pcds, reps);
    k_pack  <<<HWDIM*HWDIM/256, 256, 0, stream>>>(masks8, masks32, dflag, pb);
    k_cov   <<<SNUM/8, 256, 0, stream>>>(mapping, pb, cntT);
    k_topk  <<<NMASK, 256, 0, stream>>>(cntT, scores, contrib, wsum, fsum);
    k_adj0  <<<dim3(64,64), dim3(16,16), 0, stream>>>(reps, out_adj, ecnt, edges, wsum, fsum, out_conf);
    k_feats <<<SNUM, 256, 0, stream>>>(pf, feats);
    k_mod   <<<1024, 64, 0, stream>>>(ecnt, edges, contrib, feats, out_adj);
}

// Round 4
// 462.558 us; speedup vs baseline: 1.3006x; 1.0081x over previous
//
#include <hip/hip_runtime.h>
#include <hip/hip_bf16.h>

#define SNUM 1024
#define PNUM 60
#define KFPS 10
#define NMASK 800
#define WORDS 25        // 800/32
#define HWDIM 256
#define FD 512
#define NPTS (SNUM*PNUM)
#define EDGE_CAP (1u<<20)

__device__ __forceinline__ float fmul(float a, float b){ return __fmul_rn(a,b); }
__device__ __forceinline__ float fadd(float a, float b){ return __fadd_rn(a,b); }
__device__ __forceinline__ float fsub(float a, float b){ return __fsub_rn(a,b); }

__device__ __forceinline__ float dist2f(float ax,float ay,float az,float bx,float by,float bz){
    float dx=fsub(ax,bx), dy=fsub(ay,by), dz=fsub(az,bz);
    return fadd(fadd(fmul(dx,dx),fmul(dy,dy)),fmul(dz,dz));
}

// ---------- 1. init (zero accumulators, detect mask dtype) + FPS, fused ----------
// grid 1024 x 64. blocks 0..63 also zero the accumulator region and scan masks[0:65536]
// for dtype detection. dflag needs no zeroing: poison 0xAA has bit0==0; detect sets bit0.
__global__ __launch_bounds__(64) void k_initfps(const float* __restrict__ pcds,
                                                float* __restrict__ reps,
                                                unsigned int* __restrict__ zbase,
                                                const unsigned char* __restrict__ m8,
                                                unsigned int* __restrict__ dflag){
    int s = blockIdx.x;
    int l = threadIdx.x;
    if (s < 64){
        int tid = s*64 + l;                    // 4096 threads
        #pragma unroll
        for (int k=0;k<8;++k){
            int wi = tid + k*4096;
            if (wi < 28673) zbase[wi] = 0u;
        }
        // detect: any stray 1-byte at non-multiple-of-4 offset => uint8 bool layout
        #pragma unroll
        for (int k=0;k<16;++k){
            int i = tid*16 + k;
            if ((i & 3) != 0 && m8[i] == 1){ atomicOr(dflag, 1u); break; }
        }
    }
    float x=0.f,y=0.f,z=0.f;
    if (l < PNUM){
        const float* p = pcds + (size_t)(s*PNUM + l)*3;
        x=p[0]; y=p[1]; z=p[2];
    }
    float x0=__shfl(x,0), y0=__shfl(y,0), z0=__shfl(z,0);
    float dist = dist2f(x,y,z,x0,y0,z0);
    int sel[KFPS];
    sel[0]=0;
    #pragma unroll
    for(int it=1; it<KFPS; ++it){
        float v = (l<PNUM)? dist : -INFINITY;
        int idx = l;
        #pragma unroll
        for(int off=32; off; off>>=1){
            float ov = __shfl_xor(v, off);
            int   oi = __shfl_xor(idx, off);
            if (ov > v || (ov==v && oi<idx)){ v=ov; idx=oi; }
        }
        sel[it]=idx;
        float sx=__shfl(x,idx), sy=__shfl(y,idx), sz=__shfl(z,idx);
        float nd = dist2f(x,y,z,sx,sy,sz);
        dist = fminf(dist, nd);
    }
    #pragma unroll
    for(int j=0;j<KFPS;++j){
        float rx=__shfl(x,sel[j]), ry=__shfl(y,sel[j]), rz=__shfl(z,sel[j]);
        if (l==0){
            float* o = reps + (size_t)(s*KFPS+j)*3;
            o[0]=rx; o[1]=ry; o[2]=rz;
        }
    }
}

// ---------- 2. pack masks -> pixel-major bitwords (dword loads, LDS-staged) ----------
// block = 256 pixels. wave wv handles words w = wv, wv+4, ... Each lane owns 4 pixels
// via one uint load (4 mask bytes) per (word,bit).
__global__ __launch_bounds__(256) void k_pack(const unsigned char* __restrict__ m8,
                                              const int* __restrict__ m32,
                                              const unsigned int* __restrict__ flag,
                                              unsigned int* __restrict__ pb){
    __shared__ unsigned int lds[256*WORDS];
    int t = threadIdx.x;
    int wv = t >> 6, lane = t & 63;
    int pixBase = blockIdx.x * 256;
    if (*flag & 1u){ // uint8 bool layout
        const unsigned int* base32 = (const unsigned int*)m8;
        int pix4 = (pixBase >> 2) + lane;
        for (int w=wv; w<WORDS; w+=4){
            unsigned int w0=0,w1=0,w2=0,w3=0;
            #pragma unroll
            for (int b=0;b<32;++b){
                unsigned int u = base32[(size_t)(w*32+b)*16384 + pix4];
                w0 |= (u & 1u) << b;
                w1 |= ((u >> 8) & 1u) << b;
                w2 |= ((u >> 16) & 1u) << b;
                w3 |= ((u >> 24) & 1u) << b;
            }
            int p4 = lane*4;
            lds[(p4+0)*WORDS+w]=w0; lds[(p4+1)*WORDS+w]=w1;
            lds[(p4+2)*WORDS+w]=w2; lds[(p4+3)*WORDS+w]=w3;
        }
    } else {     // int32 layout fallback
        for (int w=wv; w<WORDS; w+=4){
            for (int i=0;i<4;++i){
                int pixel = pixBase + lane*4 + i;
                unsigned int word = 0;
                #pragma unroll
                for (int b=0;b<32;++b)
                    word |= (unsigned int)(m32[(size_t)(w*32+b)*65536 + pixel] & 1) << b;
                lds[(lane*4+i)*WORDS+w] = word;
            }
        }
    }
    __syncthreads();
    uint4* out4 = (uint4*)(pb + (size_t)pixBase*WORDS);
    const uint4* l4 = (const uint4*)lds;
    for (int u=t; u<1600; u+=256) out4[u] = l4[u];
}

// ---------- 3. coverage counts (pix fused, LDS-staged, byte-packed acc) ----------
__global__ __launch_bounds__(256) void k_cov(const int* __restrict__ mapping,
                                             const unsigned int* __restrict__ pb,
                                             unsigned char* __restrict__ cntT){
    __shared__ int pxl[8][PNUM];
    int t = threadIdx.x;
    int sBase = blockIdx.x * 8;
    for (int idx=t; idx<8*PNUM; idx+=256){
        int ls = idx / PNUM, p = idx - ls*PNUM;
        const int4 v = ((const int4*)mapping)[(sBase+ls)*PNUM + p];
        int y = min(max(v.y,0),HWDIM-1), x = min(max(v.z,0),HWDIM-1);
        pxl[ls][p] = (v.w==1) ? ((y<<8)|x) : -1;
    }
    __syncthreads();
    int ls = t >> 5, w = t & 31;
    if (w >= WORDS) return;
    unsigned int acc8[8];
    #pragma unroll
    for (int k=0;k<8;++k) acc8[k]=0;
    #pragma unroll 6
    for (int p=0;p<PNUM;++p){
        int px = pxl[ls][p];
        if (px >= 0){
            unsigned int word = pb[(size_t)px*WORDS + w];
            #pragma unroll
            for (int k=0;k<8;++k)
                acc8[k] += (word >> k) & 0x01010101u;
        }
    }
    int s = sBase + ls;
    #pragma unroll
    for (int k=0;k<8;++k)
        #pragma unroll
        for (int j=0;j<4;++j){
            int b = k + 8*j;
            cntT[(size_t)(w*32+b)*SNUM + s] = (unsigned char)((acc8[k] >> (8*j)) & 0xFF);
        }
}

// ---------- 4. stable top-10 per mask + contrib bits + conf sums ----------
__global__ __launch_bounds__(256) void k_topk(const unsigned char* __restrict__ cntT,
                                              const float* __restrict__ scores,
                                              unsigned int* __restrict__ contrib,
                                              float* __restrict__ wsum,
                                              float* __restrict__ fsum){
    int m = blockIdx.x;
    int t = threadIdx.x;
    __shared__ int hist[64];
    __shared__ int scan_s[256];
    __shared__ int sT, sR;
    if (t < 64) hist[t]=0;
    __syncthreads();
    uchar4 c4 = ((const uchar4*)(cntT + (size_t)m*SNUM))[t];
    int c[4] = {(int)c4.x,(int)c4.y,(int)c4.z,(int)c4.w};
    atomicAdd(&hist[c[0]],1); atomicAdd(&hist[c[1]],1);
    atomicAdd(&hist[c[2]],1); atomicAdd(&hist[c[3]],1);
    __syncthreads();
    if (t==0){
        int running=0, T=0, r=10;
        for(int v=63;v>=0;--v){
            int nr = running + hist[v];
            if (nr >= 10){ T=v; r=10-running; break; }
            running = nr;
        }
        sT=T; sR=r;
    }
    __syncthreads();
    int T=sT, r=sR;
    int eq = (c[0]==T)+(c[1]==T)+(c[2]==T)+(c[3]==T);
    scan_s[t]=eq; __syncthreads();
    for(int off=1;off<256;off<<=1){
        int v = (t>=off)? scan_s[t-off] : 0;
        __syncthreads();
        scan_s[t]+=v;
        __syncthreads();
    }
    int rank = scan_s[t]-eq;
    float sc = scores[m];
    #pragma unroll
    for(int j=0;j<4;++j){
        int s = t*4+j;
        bool selv = (c[j]>T) || (c[j]==T && rank<r);
        if (c[j]==T) rank++;
        if (selv && c[j]>0){
            float frac = (float)c[j]/60.0f;
            atomicAdd(&wsum[s], frac*sc);
            atomicAdd(&fsum[s], frac);
            if (c[j] >= 12)
                atomicOr(&contrib[s*WORDS + (m>>5)], 1u<<(m&31));
        }
    }
}

// ---------- 5. adj0 + edge list + needed flags + fused confidence ----------
__global__ __launch_bounds__(256) void k_adj0(const float* __restrict__ reps,
                                              float* __restrict__ out,
                                              unsigned int* __restrict__ ecnt,
                                              unsigned int* __restrict__ edges,
                                              unsigned int* __restrict__ needed,
                                              const float* __restrict__ wsum,
                                              const float* __restrict__ fsum,
                                              float* __restrict__ conf){
    __shared__ float ri[16][KFPS][3], rj[16][KFPS][3];
    __shared__ float sqi[16][KFPS], sqj[16][KFPS];
    int tx = threadIdx.x, ty = threadIdx.y;
    int t = ty*16+tx;
    if (blockIdx.y==0 && blockIdx.x<4){
        int s = blockIdx.x*256 + t;
        conf[s] = fmaxf(wsum[s]/(fsum[s]+1e-6f), 0.0f);
    }
    int i0 = blockIdx.y*16, j0 = blockIdx.x*16;
    for(int u=t; u<16*KFPS*3; u+=256){
        ((float*)ri)[u] = reps[(size_t)i0*KFPS*3 + u];
        ((float*)rj)[u] = reps[(size_t)j0*KFPS*3 + u];
    }
    __syncthreads();
    if (t < 16*KFPS){
        int sp=t/KFPS, k=t%KFPS;
        float x=ri[sp][k][0], y=ri[sp][k][1], z=ri[sp][k][2];
        sqi[sp][k]=fadd(fadd(fmul(x,x),fmul(y,y)),fmul(z,z));
        x=rj[sp][k][0]; y=rj[sp][k][1]; z=rj[sp][k][2];
        sqj[sp][k]=fadd(fadd(fmul(x,x),fmul(y,y)),fmul(z,z));
    }
    __syncthreads();
    int i = i0+ty, j = j0+tx;
    float m2 = INFINITY;
    #pragma unroll 2
    for(int k=0;k<KFPS;++k){
        float ax=ri[ty][k][0], ay=ri[ty][k][1], az=ri[ty][k][2], as=sqi[ty][k];
        #pragma unroll
        for(int l=0;l<KFPS;++l){
            float dot = fadd(fadd(fmul(ax,rj[tx][l][0]),fmul(ay,rj[tx][l][1])),fmul(az,rj[tx][l][2]));
            float d2 = fmaxf(fsub(fadd(as,sqj[tx][l]), fmul(2.0f,dot)), 0.0f);
            m2 = fminf(m2,d2);
        }
    }
    float d = sqrtf(fadd(m2,1e-12f));
    bool edge = (d < 0.2f) && (i!=j);
    out[(size_t)i*SNUM + j] = edge ? expf(-d) : 0.0f;
    if (edge){
        unsigned int e = atomicAdd(ecnt, 1u);
        if (e < EDGE_CAP) edges[e] = ((unsigned int)i<<10) | (unsigned int)j;
        atomicOr(&needed[i], 1u);
        atomicOr(&needed[j], 1u);
    }
}

// ---------- 6. normalized mean features (gated by edge incidence) ----------
__global__ __launch_bounds__(256) void k_feats(const float* __restrict__ pf,
                                               const unsigned int* __restrict__ needed,
                                               float* __restrict__ feats){
    int s = blockIdx.x, t = threadIdx.x;
    if (!needed[s]) return;
    int g = t >> 7;
    int c = t & 127;
    const float4* pf4 = (const float4*)pf;
    float4 a = make_float4(0.f,0.f,0.f,0.f);
    for (int p=g; p<PNUM; p+=2){
        float4 v = pf4[(size_t)(s*PNUM+p)*128 + c];
        a.x+=v.x; a.y+=v.y; a.z+=v.z; a.w+=v.w;
    }
    __shared__ float4 part[2][128];
    part[g][c] = a;
    __shared__ float red[256];
    __syncthreads();
    float4 m = make_float4(0.f,0.f,0.f,0.f);
    float ss = 0.f;
    if (g==0){
        float4 b = part[1][c];
        m.x=(a.x+b.x)/60.0f; m.y=(a.y+b.y)/60.0f; m.z=(a.z+b.z)/60.0f; m.w=(a.w+b.w)/60.0f;
        ss = m.x*m.x + m.y*m.y + m.z*m.z + m.w*m.w;
    }
    red[t] = ss; __syncthreads();
    for (int off=128; off; off>>=1){ if (t<off) red[t]+=red[t+off]; __syncthreads(); }
    float denom = fmaxf(sqrtf(red[0]), 1e-12f);
    if (g==0){
        float4 o; o.x=m.x/denom; o.y=m.y/denom; o.z=m.z/denom; o.w=m.w/denom;
        ((float4*)feats)[(size_t)s*128 + c] = o;
    }
}

// ---------- 7. mod per edge, fold into adjacency ----------
__global__ __launch_bounds__(64) void k_mod(const unsigned int* __restrict__ ecnt,
                                            const unsigned int* __restrict__ edges,
                                            const unsigned int* __restrict__ contrib,
                                            const float* __restrict__ feats,
                                            float* __restrict__ out){
    unsigned int n = *ecnt; if (n > EDGE_CAP) n = EDGE_CAP;
    int lane = threadIdx.x;
    for (unsigned int e = blockIdx.x; e < n; e += gridDim.x){
        unsigned int pk = edges[e];
        int i = (int)(pk>>10), j = (int)(pk & 1023u);
        const float4* fi = (const float4*)(feats + (size_t)i*FD);
        const float4* fj = (const float4*)(feats + (size_t)j*FD);
        float dot = 0.f;
        #pragma unroll
        for(int r=0;r<2;++r){
            float4 a = fi[lane + 64*r], b = fj[lane + 64*r];
            dot += a.x*b.x + a.y*b.y + a.z*b.z + a.w*b.w;
        }
        #pragma unroll
        for(int off=32;off;off>>=1) dot += __shfl_xor(dot,off);

        unsigned int u=0, aw=0; int cw=0;
        if (lane < WORDS){
            unsigned int bi = contrib[i*WORDS+lane], bj = contrib[j*WORDS+lane];
            u = bi|bj; aw = bi&bj; cw = __popc(u);
        }
        int pre=0, ctot=0;
        for(int k2=0;k2<WORDS;++k2){
            int v=__shfl(cw,k2);
            ctot += v;
            if (k2<lane) pre += v;
        }
        int il=0;
        if (lane<WORDS && pre<5){
            unsigned int x=u;
            int lim = 5-pre;
            #pragma unroll
            for(int q=0;q<5;++q){
                if (q<lim && x){
                    int b = __ffs(x)-1;
                    il += (int)((aw>>b)&1u);
                    x &= x-1;
                }
            }
        }
        #pragma unroll
        for(int off=32;off;off>>=1) il += __shfl_xor(il,off);
        int uni = min(ctot,5);
        float ov = (float)il / ((float)uni + 1e-6f);
        float sim = fminf(fmaxf((dot+1.0f)*0.5f,0.0f),1.0f);
        if (sim < 0.5f) sim = 1.0f;
        float mod = ov*sim;
        if (lane==0){
            size_t o = (size_t)i*SNUM+j;
            out[o] = fmaxf(out[o], mod);
        }
    }
}

extern "C" void kernel_launch(void* const* d_in, const int* in_sizes, int n_in,
                              void* d_out, int out_size, void* d_ws, size_t ws_size,
                              hipStream_t stream){
    const float*         pcds    = (const float*)d_in[0];
    const unsigned char* masks8  = (const unsigned char*)d_in[2];
    const int*           masks32 = (const int*)d_in[2];
    const int*           mapping = (const int*)d_in[3];
    const float*         scores  = (const float*)d_in[4];
    const float*         pf      = (const float*)d_in[5];
    float* out_adj  = (float*)d_out;
    float* out_conf = out_adj + (size_t)SNUM*SNUM;

    char* ws = (char*)d_ws;
    float*         reps    = (float*)(ws + 0);               // 122880 B
    unsigned int*  pb      = (unsigned int*)(ws + 131072);   // 6553600 B
    unsigned char* cntT    = (unsigned char*)(ws + 6684672); // 819200 B
    unsigned int*  contrib = (unsigned int*)(ws + 7503872);  // 102400 B  [zeroed in k_initfps]
    float*         wsum    = (float*)(ws + 7606272);         // 4096 B    [zeroed]
    float*         fsum    = (float*)(ws + 7610368);         // 4096 B    [zeroed]
    unsigned int*  needed  = (unsigned int*)(ws + 7614464);  // 4096 B    [zeroed]
    unsigned int*  ecnt    = (unsigned int*)(ws + 7618560);  // 4 B       [zeroed]
    unsigned int*  dflag   = (unsigned int*)(ws + 7618564);  // 4 B  (bit0 test; 0xAA poison has bit0==0)
    unsigned int*  edges   = (unsigned int*)(ws + 7618568);  // 4 MB (cap 1M edges)
    float*         feats   = (float*)(ws + 11812880);        // 2 MB; total ~13.9 MB
    unsigned int*  zbase   = (unsigned int*)(ws + 7503872);  // 28673 words zero region

    k_initfps<<<SNUM, 64, 0, stream>>>(pcds, reps, zbase, masks8, dflag);
    k_pack   <<<HWDIM*HWDIM/256, 256, 0, stream>>>(masks8, masks32, dflag, pb);
    k_cov    <<<SNUM/8, 256, 0, stream>>>(mapping, pb, cntT);
    k_topk   <<<NMASK, 256, 0, stream>>>(cntT, scores, contrib, wsum, fsum);
    k_adj0   <<<dim3(64,64), dim3(16,16), 0, stream>>>(reps, out_adj, ecnt, edges, needed, wsum, fsum, out_conf);
    k_feats  <<<SNUM, 256, 0, stream>>>(pf, needed, feats);
    k_mod    <<<1024, 64, 0, stream>>>(ecnt, edges, contrib, feats, out_adj);
}

// Round 5
// 431.965 us; speedup vs baseline: 1.3927x; 1.0708x over previous
//
#include <hip/hip_runtime.h>
#include <hip/hip_bf16.h>

#define SNUM 1024
#define PNUM 60
#define KFPS 10
#define NMASK 800
#define WORDS 25        // 800/32
#define HWDIM 256
#define FD 512
#define NPTS (SNUM*PNUM)
#define EDGE_CAP (1u<<20)
#define NTILE 2080      // 64*65/2 upper-triangular 16x16 tiles

__device__ __forceinline__ float fmul(float a, float b){ return __fmul_rn(a,b); }
__device__ __forceinline__ float fadd(float a, float b){ return __fadd_rn(a,b); }
__device__ __forceinline__ float fsub(float a, float b){ return __fsub_rn(a,b); }

__device__ __forceinline__ float dist2f(float ax,float ay,float az,float bx,float by,float bz){
    float dx=fsub(ax,bx), dy=fsub(ay,by), dz=fsub(az,bz);
    return fadd(fadd(fmul(dx,dx),fmul(dy,dy)),fmul(dz,dz));
}

// ---------- 1. init (zero accumulators, detect mask dtype) + FPS, fused ----------
__global__ __launch_bounds__(64) void k_initfps(const float* __restrict__ pcds,
                                                float* __restrict__ reps,
                                                unsigned int* __restrict__ zbase,
                                                const unsigned char* __restrict__ m8,
                                                unsigned int* __restrict__ dflag){
    int s = blockIdx.x;
    int l = threadIdx.x;
    if (s < 64){
        int tid = s*64 + l;                    // 4096 threads
        #pragma unroll
        for (int k=0;k<8;++k){
            int wi = tid + k*4096;
            if (wi < 28673) zbase[wi] = 0u;
        }
        // detect: any stray 1-byte at non-multiple-of-4 offset => uint8 bool layout
        #pragma unroll
        for (int k=0;k<16;++k){
            int i = tid*16 + k;
            if ((i & 3) != 0 && m8[i] == 1){ atomicOr(dflag, 1u); break; }
        }
    }
    float x=0.f,y=0.f,z=0.f;
    if (l < PNUM){
        const float* p = pcds + (size_t)(s*PNUM + l)*3;
        x=p[0]; y=p[1]; z=p[2];
    }
    float x0=__shfl(x,0), y0=__shfl(y,0), z0=__shfl(z,0);
    float dist = dist2f(x,y,z,x0,y0,z0);
    int sel[KFPS];
    sel[0]=0;
    #pragma unroll
    for(int it=1; it<KFPS; ++it){
        float v = (l<PNUM)? dist : -INFINITY;
        int idx = l;
        #pragma unroll
        for(int off=32; off; off>>=1){
            float ov = __shfl_xor(v, off);
            int   oi = __shfl_xor(idx, off);
            if (ov > v || (ov==v && oi<idx)){ v=ov; idx=oi; }
        }
        sel[it]=idx;
        float sx=__shfl(x,idx), sy=__shfl(y,idx), sz=__shfl(z,idx);
        float nd = dist2f(x,y,z,sx,sy,sz);
        dist = fminf(dist, nd);
    }
    #pragma unroll
    for(int j=0;j<KFPS;++j){
        float rx=__shfl(x,sel[j]), ry=__shfl(y,sel[j]), rz=__shfl(z,sel[j]);
        if (l==0){
            float* o = reps + (size_t)(s*KFPS+j)*3;
            o[0]=rx; o[1]=ry; o[2]=rz;
        }
    }
}

// ---------- 2. pack masks -> pixel-major bitwords (dword loads, LDS-staged) ----------
__global__ __launch_bounds__(256) void k_pack(const unsigned char* __restrict__ m8,
                                              const int* __restrict__ m32,
                                              const unsigned int* __restrict__ flag,
                                              unsigned int* __restrict__ pb){
    __shared__ unsigned int lds[256*WORDS];
    int t = threadIdx.x;
    int wv = t >> 6, lane = t & 63;
    int pixBase = blockIdx.x * 256;
    if (*flag & 1u){ // uint8 bool layout
        const unsigned int* base32 = (const unsigned int*)m8;
        int pix4 = (pixBase >> 2) + lane;
        for (int w=wv; w<WORDS; w+=4){
            unsigned int w0=0,w1=0,w2=0,w3=0;
            #pragma unroll
            for (int b=0;b<32;++b){
                unsigned int u = base32[(size_t)(w*32+b)*16384 + pix4];
                w0 |= (u & 1u) << b;
                w1 |= ((u >> 8) & 1u) << b;
                w2 |= ((u >> 16) & 1u) << b;
                w3 |= ((u >> 24) & 1u) << b;
            }
            int p4 = lane*4;
            lds[(p4+0)*WORDS+w]=w0; lds[(p4+1)*WORDS+w]=w1;
            lds[(p4+2)*WORDS+w]=w2; lds[(p4+3)*WORDS+w]=w3;
        }
    } else {     // int32 layout fallback
        for (int w=wv; w<WORDS; w+=4){
            for (int i=0;i<4;++i){
                int pixel = pixBase + lane*4 + i;
                unsigned int word = 0;
                #pragma unroll
                for (int b=0;b<32;++b)
                    word |= (unsigned int)(m32[(size_t)(w*32+b)*65536 + pixel] & 1) << b;
                lds[(lane*4+i)*WORDS+w] = word;
            }
        }
    }
    __syncthreads();
    uint4* out4 = (uint4*)(pb + (size_t)pixBase*WORDS);
    const uint4* l4 = (const uint4*)lds;
    for (int u=t; u<1600; u+=256) out4[u] = l4[u];
}

// ---------- 3. fused: triangular adj0 tiles [0,2080) + coverage counts [2080,2208) ----------
__global__ __launch_bounds__(256) void k_covadj(const float* __restrict__ reps,
                                                const int* __restrict__ mapping,
                                                const unsigned int* __restrict__ pb,
                                                unsigned char* __restrict__ cntT,
                                                float* __restrict__ out,
                                                unsigned int* __restrict__ ecnt,
                                                unsigned int* __restrict__ edges,
                                                unsigned int* __restrict__ needed){
    int bid = blockIdx.x;
    int t = threadIdx.x;
    if (bid < NTILE){
        // ---- adj role: upper-triangular tile (it,jt), it<=jt ----
        int rem = bid, it = 0;
        while (rem >= 64 - it){ rem -= 64 - it; ++it; }
        int jt = it + rem;
        __shared__ float ri[16][KFPS][3], rj[16][KFPS][3];
        __shared__ float sqi[16][KFPS], sqj[16][KFPS];
        __shared__ float tile[16][17];
        int tx = t & 15, ty = t >> 4;
        int i0 = it*16, j0 = jt*16;
        for(int u=t; u<16*KFPS*3; u+=256){
            ((float*)ri)[u] = reps[(size_t)i0*KFPS*3 + u];
            ((float*)rj)[u] = reps[(size_t)j0*KFPS*3 + u];
        }
        __syncthreads();
        if (t < 16*KFPS){
            int sp=t/KFPS, k=t%KFPS;
            float x=ri[sp][k][0], y=ri[sp][k][1], z=ri[sp][k][2];
            sqi[sp][k]=fadd(fadd(fmul(x,x),fmul(y,y)),fmul(z,z));
            x=rj[sp][k][0]; y=rj[sp][k][1]; z=rj[sp][k][2];
            sqj[sp][k]=fadd(fadd(fmul(x,x),fmul(y,y)),fmul(z,z));
        }
        __syncthreads();
        int i = i0+ty, j = j0+tx;
        float m2 = INFINITY;
        #pragma unroll 2
        for(int k=0;k<KFPS;++k){
            float ax=ri[ty][k][0], ay=ri[ty][k][1], az=ri[ty][k][2], as=sqi[ty][k];
            #pragma unroll
            for(int l=0;l<KFPS;++l){
                float dot = fadd(fadd(fmul(ax,rj[tx][l][0]),fmul(ay,rj[tx][l][1])),fmul(az,rj[tx][l][2]));
                float d2 = fmaxf(fsub(fadd(as,sqj[tx][l]), fmul(2.0f,dot)), 0.0f);
                m2 = fminf(m2,d2);
            }
        }
        float d = sqrtf(fadd(m2,1e-12f));
        bool edge = (d < 0.2f) && (i!=j);
        float v = edge ? expf(-d) : 0.0f;
        out[(size_t)i*SNUM + j] = v;
        tile[ty][tx] = v;
        if (edge){
            if (it != jt){
                unsigned int e = atomicAdd(ecnt, 2u);
                if (e+1 < EDGE_CAP){
                    edges[e]   = ((unsigned int)i<<10) | (unsigned int)j;
                    edges[e+1] = ((unsigned int)j<<10) | (unsigned int)i;
                }
            } else {
                unsigned int e = atomicAdd(ecnt, 1u);
                if (e < EDGE_CAP) edges[e] = ((unsigned int)i<<10) | (unsigned int)j;
            }
            atomicOr(&needed[i], 1u);
            atomicOr(&needed[j], 1u);
        }
        if (it != jt){
            __syncthreads();
            // mirror: out[j0+ty][i0+tx] = v(i0+tx, j0+ty) = tile[tx][ty]
            out[(size_t)(j0+ty)*SNUM + i0 + tx] = tile[tx][ty];
        }
    } else {
        // ---- cov role ----
        __shared__ int pxl[8][PNUM];
        int sBase = (bid - NTILE) * 8;
        for (int idx=t; idx<8*PNUM; idx+=256){
            int ls = idx / PNUM, p = idx - ls*PNUM;
            const int4 v = ((const int4*)mapping)[(sBase+ls)*PNUM + p];
            int y = min(max(v.y,0),HWDIM-1), x = min(max(v.z,0),HWDIM-1);
            pxl[ls][p] = (v.w==1) ? ((y<<8)|x) : -1;
        }
        __syncthreads();
        int ls = t >> 5, w = t & 31;
        if (w >= WORDS) return;
        unsigned int acc8[8];
        #pragma unroll
        for (int k=0;k<8;++k) acc8[k]=0;
        #pragma unroll 6
        for (int p=0;p<PNUM;++p){
            int px = pxl[ls][p];
            if (px >= 0){
                unsigned int word = pb[(size_t)px*WORDS + w];
                #pragma unroll
                for (int k=0;k<8;++k)
                    acc8[k] += (word >> k) & 0x01010101u;
            }
        }
        int s = sBase + ls;
        #pragma unroll
        for (int k=0;k<8;++k)
            #pragma unroll
            for (int j=0;j<4;++j){
                int b = k + 8*j;
                cntT[(size_t)(w*32+b)*SNUM + s] = (unsigned char)((acc8[k] >> (8*j)) & 0xFF);
            }
    }
}

// ---------- 4. fused: top-10 per mask [0,800) + gated mean features [800,1824) ----------
__global__ __launch_bounds__(256) void k_topkfeats(const unsigned char* __restrict__ cntT,
                                                   const float* __restrict__ scores,
                                                   unsigned int* __restrict__ contrib,
                                                   float* __restrict__ wsum,
                                                   float* __restrict__ fsum,
                                                   const float* __restrict__ pf,
                                                   const unsigned int* __restrict__ needed,
                                                   float* __restrict__ feats){
    int bid = blockIdx.x;
    int t = threadIdx.x;
    if (bid < NMASK){
        // ---- topk role ----
        int m = bid;
        __shared__ int hist[64];
        __shared__ int wsums[4];
        __shared__ int sT, sR;
        if (t < 64) hist[t]=0;
        __syncthreads();
        uchar4 c4 = ((const uchar4*)(cntT + (size_t)m*SNUM))[t];
        int c[4] = {(int)c4.x,(int)c4.y,(int)c4.z,(int)c4.w};
        atomicAdd(&hist[c[0]],1); atomicAdd(&hist[c[1]],1);
        atomicAdd(&hist[c[2]],1); atomicAdd(&hist[c[3]],1);
        __syncthreads();
        if (t==0){
            int running=0, T=0, r=10;
            for(int v=63;v>=0;--v){
                int nr = running + hist[v];
                if (nr >= 10){ T=v; r=10-running; break; }
                running = nr;
            }
            sT=T; sR=r;
        }
        __syncthreads();
        int T=sT, r=sR;
        int eq = (c[0]==T)+(c[1]==T)+(c[2]==T)+(c[3]==T);
        // 64-lane inclusive shfl scan + cross-wave offsets
        int incl = eq;
        #pragma unroll
        for (int off=1; off<64; off<<=1){
            int v = __shfl_up(incl, off);
            if ((t & 63) >= off) incl += v;
        }
        if ((t & 63) == 63) wsums[t>>6] = incl;
        __syncthreads();
        int base = 0;
        #pragma unroll
        for (int wv=0; wv<4; ++wv)
            if (wv < (t>>6)) base += wsums[wv];
        int rank = base + incl - eq;   // exclusive prefix of (cnt==T) by index
        float sc = scores[m];
        #pragma unroll
        for(int j=0;j<4;++j){
            int s = t*4+j;
            bool selv = (c[j]>T) || (c[j]==T && rank<r);
            if (c[j]==T) rank++;
            if (selv && c[j]>0){
                float frac = (float)c[j]/60.0f;
                atomicAdd(&wsum[s], frac*sc);
                atomicAdd(&fsum[s], frac);
                if (c[j] >= 12)
                    atomicOr(&contrib[s*WORDS + (m>>5)], 1u<<(m&31));
            }
        }
    } else {
        // ---- feats role (gated by edge incidence) ----
        int s = bid - NMASK;
        if (!needed[s]) return;
        int g = t >> 7;
        int c = t & 127;
        const float4* pf4 = (const float4*)pf;
        float4 a = make_float4(0.f,0.f,0.f,0.f);
        for (int p=g; p<PNUM; p+=2){
            float4 v = pf4[(size_t)(s*PNUM+p)*128 + c];
            a.x+=v.x; a.y+=v.y; a.z+=v.z; a.w+=v.w;
        }
        __shared__ float4 part[2][128];
        part[g][c] = a;
        __shared__ float red[256];
        __syncthreads();
        float4 m = make_float4(0.f,0.f,0.f,0.f);
        float ss = 0.f;
        if (g==0){
            float4 b = part[1][c];
            m.x=(a.x+b.x)/60.0f; m.y=(a.y+b.y)/60.0f; m.z=(a.z+b.z)/60.0f; m.w=(a.w+b.w)/60.0f;
            ss = m.x*m.x + m.y*m.y + m.z*m.z + m.w*m.w;
        }
        red[t] = ss; __syncthreads();
        for (int off=128; off; off>>=1){ if (t<off) red[t]+=red[t+off]; __syncthreads(); }
        float denom = fmaxf(sqrtf(red[0]), 1e-12f);
        if (g==0){
            float4 o; o.x=m.x/denom; o.y=m.y/denom; o.z=m.z/denom; o.w=m.w/denom;
            ((float4*)feats)[(size_t)s*128 + c] = o;
        }
    }
}

// ---------- 5. mod per edge + fused confidence ----------
__global__ __launch_bounds__(64) void k_mod(const unsigned int* __restrict__ ecnt,
                                            const unsigned int* __restrict__ edges,
                                            const unsigned int* __restrict__ contrib,
                                            const float* __restrict__ feats,
                                            const float* __restrict__ wsum,
                                            const float* __restrict__ fsum,
                                            float* __restrict__ conf,
                                            float* __restrict__ out){
    int lane = threadIdx.x;
    if (blockIdx.x < 16){
        int s = blockIdx.x*64 + lane;
        conf[s] = fmaxf(wsum[s]/(fsum[s]+1e-6f), 0.0f);
    }
    unsigned int n = *ecnt; if (n > EDGE_CAP) n = EDGE_CAP;
    for (unsigned int e = blockIdx.x; e < n; e += gridDim.x){
        unsigned int pk = edges[e];
        int i = (int)(pk>>10), j = (int)(pk & 1023u);
        const float4* fi = (const float4*)(feats + (size_t)i*FD);
        const float4* fj = (const float4*)(feats + (size_t)j*FD);
        float dot = 0.f;
        #pragma unroll
        for(int r=0;r<2;++r){
            float4 a = fi[lane + 64*r], b = fj[lane + 64*r];
            dot += a.x*b.x + a.y*b.y + a.z*b.z + a.w*b.w;
        }
        #pragma unroll
        for(int off=32;off;off>>=1) dot += __shfl_xor(dot,off);

        unsigned int u=0, aw=0; int cw=0;
        if (lane < WORDS){
            unsigned int bi = contrib[i*WORDS+lane], bj = contrib[j*WORDS+lane];
            u = bi|bj; aw = bi&bj; cw = __popc(u);
        }
        int pre=0, ctot=0;
        for(int k2=0;k2<WORDS;++k2){
            int v=__shfl(cw,k2);
            ctot += v;
            if (k2<lane) pre += v;
        }
        int il=0;
        if (lane<WORDS && pre<5){
            unsigned int x=u;
            int lim = 5-pre;
            #pragma unroll
            for(int q=0;q<5;++q){
                if (q<lim && x){
                    int b = __ffs(x)-1;
                    il += (int)((aw>>b)&1u);
                    x &= x-1;
                }
            }
        }
        #pragma unroll
        for(int off=32;off;off>>=1) il += __shfl_xor(il,off);
        int uni = min(ctot,5);
        float ov = (float)il / ((float)uni + 1e-6f);
        float sim = fminf(fmaxf((dot+1.0f)*0.5f,0.0f),1.0f);
        if (sim < 0.5f) sim = 1.0f;
        float mod = ov*sim;
        if (lane==0){
            size_t o = (size_t)i*SNUM+j;
            out[o] = fmaxf(out[o], mod);
        }
    }
}

extern "C" void kernel_launch(void* const* d_in, const int* in_sizes, int n_in,
                              void* d_out, int out_size, void* d_ws, size_t ws_size,
                              hipStream_t stream){
    const float*         pcds    = (const float*)d_in[0];
    const unsigned char* masks8  = (const unsigned char*)d_in[2];
    const int*           masks32 = (const int*)d_in[2];
    const int*           mapping = (const int*)d_in[3];
    const float*         scores  = (const float*)d_in[4];
    const float*         pf      = (const float*)d_in[5];
    float* out_adj  = (float*)d_out;
    float* out_conf = out_adj + (size_t)SNUM*SNUM;

    char* ws = (char*)d_ws;
    float*         reps    = (float*)(ws + 0);               // 122880 B
    unsigned int*  pb      = (unsigned int*)(ws + 131072);   // 6553600 B
    unsigned char* cntT    = (unsigned char*)(ws + 6684672); // 819200 B
    unsigned int*  contrib = (unsigned int*)(ws + 7503872);  // 102400 B  [zeroed in k_initfps]
    float*         wsum    = (float*)(ws + 7606272);         // 4096 B    [zeroed]
    float*         fsum    = (float*)(ws + 7610368);         // 4096 B    [zeroed]
    unsigned int*  needed  = (unsigned int*)(ws + 7614464);  // 4096 B    [zeroed]
    unsigned int*  ecnt    = (unsigned int*)(ws + 7618560);  // 4 B       [zeroed]
    unsigned int*  dflag   = (unsigned int*)(ws + 7618564);  // 4 B  (bit0 test; 0xAA poison has bit0==0)
    unsigned int*  edges   = (unsigned int*)(ws + 7618568);  // 4 MB (cap 1M edges)
    float*         feats   = (float*)(ws + 11812880);        // 2 MB; total ~13.9 MB
    unsigned int*  zbase   = (unsigned int*)(ws + 7503872);  // 28673 words zero region

    k_initfps  <<<SNUM, 64, 0, stream>>>(pcds, reps, zbase, masks8, dflag);
    k_pack     <<<HWDIM*HWDIM/256, 256, 0, stream>>>(masks8, masks32, dflag, pb);
    k_covadj   <<<NTILE + SNUM/8, 256, 0, stream>>>(reps, mapping, pb, cntT, out_adj, ecnt, edges, needed);
    k_topkfeats<<<NMASK + SNUM, 256, 0, stream>>>(cntT, scores, contrib, wsum, fsum, pf, needed, feats);
    k_mod      <<<1024, 64, 0, stream>>>(ecnt, edges, contrib, feats, wsum, fsum, out_conf, out_adj);
}

// Round 6
// 424.518 us; speedup vs baseline: 1.4171x; 1.0175x over previous
//
#include <hip/hip_runtime.h>
#include <hip/hip_bf16.h>

#define SNUM 1024
#define PNUM 60
#define KFPS 10
#define NMASK 800
#define WORDS 25        // 800/32
#define HWDIM 256
#define FD 512
#define NPTS (SNUM*PNUM)
#define EDGE_CAP (1u<<20)
#define NTILE 2080      // 64*65/2 upper-triangular 16x16 tiles

__device__ __forceinline__ float fmul(float a, float b){ return __fmul_rn(a,b); }
__device__ __forceinline__ float fadd(float a, float b){ return __fadd_rn(a,b); }
__device__ __forceinline__ float fsub(float a, float b){ return __fsub_rn(a,b); }

__device__ __forceinline__ float dist2f(float ax,float ay,float az,float bx,float by,float bz){
    float dx=fsub(ax,bx), dy=fsub(ay,by), dz=fsub(az,bz);
    return fadd(fadd(fmul(dx,dx),fmul(dy,dy)),fmul(dz,dz));
}

// ---------- 1. fused: FPS+zero [0,128) | pack masks (per-block dtype detect) [128,384) ----------
// 512 threads. FPS role: 8 waves = 8 superpoints per block; blocks 0..63 also zero accumulators.
// Pack role: detect uint8-vs-int32 from first 16KB (block-local, consistent), then pack
// 256 pixels x 25 words into pixel-major bitwords via LDS, coalesced uint4 out.
__global__ __launch_bounds__(512) void k_init(const float* __restrict__ pcds,
                                              float* __restrict__ reps,
                                              unsigned int* __restrict__ zbase,
                                              const unsigned char* __restrict__ m8,
                                              unsigned int* __restrict__ pb){
    int bid = blockIdx.x;
    int t = threadIdx.x;
    if (bid < 128){
        // ---- FPS + zero role ----
        if (bid < 64){
            int tid = bid*512 + t;             // 32768 threads cover 28673 words
            if (tid < 28673) zbase[tid] = 0u;
        }
        int wave = t >> 6, l = t & 63;
        int s = bid*8 + wave;
        float x=0.f,y=0.f,z=0.f;
        if (l < PNUM){
            const float* p = pcds + (size_t)(s*PNUM + l)*3;
            x=p[0]; y=p[1]; z=p[2];
        }
        float x0=__shfl(x,0), y0=__shfl(y,0), z0=__shfl(z,0);
        float dist = dist2f(x,y,z,x0,y0,z0);
        int sel[KFPS];
        sel[0]=0;
        #pragma unroll
        for(int it=1; it<KFPS; ++it){
            float v = (l<PNUM)? dist : -INFINITY;
            int idx = l;
            #pragma unroll
            for(int off=32; off; off>>=1){
                float ov = __shfl_xor(v, off);
                int   oi = __shfl_xor(idx, off);
                if (ov > v || (ov==v && oi<idx)){ v=ov; idx=oi; }
            }
            sel[it]=idx;
            float sx=__shfl(x,idx), sy=__shfl(y,idx), sz=__shfl(z,idx);
            float nd = dist2f(x,y,z,sx,sy,sz);
            dist = fminf(dist, nd);
        }
        #pragma unroll
        for(int j=0;j<KFPS;++j){
            float rx=__shfl(x,sel[j]), ry=__shfl(y,sel[j]), rz=__shfl(z,sel[j]);
            if (l==0){
                float* o = reps + (size_t)(s*KFPS+j)*3;
                o[0]=rx; o[1]=ry; o[2]=rz;
            }
        }
    } else {
        // ---- pack role ----
        __shared__ unsigned int lds[256*WORDS];
        __shared__ int s_u8;
        const unsigned int* base32 = (const unsigned int*)m8;
        const int* m32 = (const int*)m8;
        if (t==0) s_u8 = 0;
        __syncthreads();
        // detect: any set byte at non-multiple-of-4 offset within first 16KB => uint8 layout
        unsigned int acc = 0;
        #pragma unroll
        for (int k=0;k<8;++k) acc |= base32[t*8+k] & 0xFFFFFF00u;
        if (acc) s_u8 = 1;
        __syncthreads();
        int wv = t >> 6, lane = t & 63;
        int pixBase = (bid - 128) * 256;
        if (s_u8){ // uint8 bool layout
            int pix4 = (pixBase >> 2) + lane;
            for (int w=wv; w<WORDS; w+=8){
                unsigned int w0=0,w1=0,w2=0,w3=0;
                #pragma unroll
                for (int b=0;b<32;++b){
                    unsigned int u = base32[(size_t)(w*32+b)*16384 + pix4];
                    w0 |= (u & 1u) << b;
                    w1 |= ((u >> 8) & 1u) << b;
                    w2 |= ((u >> 16) & 1u) << b;
                    w3 |= ((u >> 24) & 1u) << b;
                }
                int p4 = lane*4;
                lds[(p4+0)*WORDS+w]=w0; lds[(p4+1)*WORDS+w]=w1;
                lds[(p4+2)*WORDS+w]=w2; lds[(p4+3)*WORDS+w]=w3;
            }
        } else {   // int32 layout fallback
            for (int w=wv; w<WORDS; w+=8){
                for (int i=0;i<4;++i){
                    int pixel = pixBase + lane*4 + i;
                    unsigned int word = 0;
                    #pragma unroll
                    for (int b=0;b<32;++b)
                        word |= (unsigned int)(m32[(size_t)(w*32+b)*65536 + pixel] & 1) << b;
                    lds[(lane*4+i)*WORDS+w] = word;
                }
            }
        }
        __syncthreads();
        uint4* out4 = (uint4*)(pb + (size_t)pixBase*WORDS);
        const uint4* l4 = (const uint4*)lds;
        for (int u=t; u<1600; u+=512) out4[u] = l4[u];
    }
}

// ---------- 2. fused: triangular adj0 tiles [0,2080) + coverage counts [2080,2208) ----------
__global__ __launch_bounds__(256) void k_covadj(const float* __restrict__ reps,
                                                const int* __restrict__ mapping,
                                                const unsigned int* __restrict__ pb,
                                                unsigned char* __restrict__ cntT,
                                                float* __restrict__ out,
                                                unsigned int* __restrict__ ecnt,
                                                unsigned int* __restrict__ edges,
                                                unsigned int* __restrict__ needed){
    int bid = blockIdx.x;
    int t = threadIdx.x;
    if (bid < NTILE){
        int rem = bid, it = 0;
        while (rem >= 64 - it){ rem -= 64 - it; ++it; }
        int jt = it + rem;
        __shared__ float ri[16][KFPS][3], rj[16][KFPS][3];
        __shared__ float sqi[16][KFPS], sqj[16][KFPS];
        __shared__ float tile[16][17];
        int tx = t & 15, ty = t >> 4;
        int i0 = it*16, j0 = jt*16;
        for(int u=t; u<16*KFPS*3; u+=256){
            ((float*)ri)[u] = reps[(size_t)i0*KFPS*3 + u];
            ((float*)rj)[u] = reps[(size_t)j0*KFPS*3 + u];
        }
        __syncthreads();
        if (t < 16*KFPS){
            int sp=t/KFPS, k=t%KFPS;
            float x=ri[sp][k][0], y=ri[sp][k][1], z=ri[sp][k][2];
            sqi[sp][k]=fadd(fadd(fmul(x,x),fmul(y,y)),fmul(z,z));
            x=rj[sp][k][0]; y=rj[sp][k][1]; z=rj[sp][k][2];
            sqj[sp][k]=fadd(fadd(fmul(x,x),fmul(y,y)),fmul(z,z));
        }
        __syncthreads();
        int i = i0+ty, j = j0+tx;
        float m2 = INFINITY;
        #pragma unroll 2
        for(int k=0;k<KFPS;++k){
            float ax=ri[ty][k][0], ay=ri[ty][k][1], az=ri[ty][k][2], as=sqi[ty][k];
            #pragma unroll
            for(int l=0;l<KFPS;++l){
                float dot = fadd(fadd(fmul(ax,rj[tx][l][0]),fmul(ay,rj[tx][l][1])),fmul(az,rj[tx][l][2]));
                float d2 = fmaxf(fsub(fadd(as,sqj[tx][l]), fmul(2.0f,dot)), 0.0f);
                m2 = fminf(m2,d2);
            }
        }
        float d = sqrtf(fadd(m2,1e-12f));
        bool edge = (d < 0.2f) && (i!=j);
        float v = edge ? expf(-d) : 0.0f;
        out[(size_t)i*SNUM + j] = v;
        tile[ty][tx] = v;
        if (edge){
            if (it != jt){
                unsigned int e = atomicAdd(ecnt, 2u);
                if (e+1 < EDGE_CAP){
                    edges[e]   = ((unsigned int)i<<10) | (unsigned int)j;
                    edges[e+1] = ((unsigned int)j<<10) | (unsigned int)i;
                }
            } else {
                unsigned int e = atomicAdd(ecnt, 1u);
                if (e < EDGE_CAP) edges[e] = ((unsigned int)i<<10) | (unsigned int)j;
            }
            atomicOr(&needed[i], 1u);
            atomicOr(&needed[j], 1u);
        }
        if (it != jt){
            __syncthreads();
            out[(size_t)(j0+ty)*SNUM + i0 + tx] = tile[tx][ty];
        }
    } else {
        __shared__ int pxl[8][PNUM];
        int sBase = (bid - NTILE) * 8;
        for (int idx=t; idx<8*PNUM; idx+=256){
            int ls = idx / PNUM, p = idx - ls*PNUM;
            const int4 v = ((const int4*)mapping)[(sBase+ls)*PNUM + p];
            int y = min(max(v.y,0),HWDIM-1), x = min(max(v.z,0),HWDIM-1);
            pxl[ls][p] = (v.w==1) ? ((y<<8)|x) : -1;
        }
        __syncthreads();
        int ls = t >> 5, w = t & 31;
        if (w >= WORDS) return;
        unsigned int acc8[8];
        #pragma unroll
        for (int k=0;k<8;++k) acc8[k]=0;
        #pragma unroll 6
        for (int p=0;p<PNUM;++p){
            int px = pxl[ls][p];
            if (px >= 0){
                unsigned int word = pb[(size_t)px*WORDS + w];
                #pragma unroll
                for (int k=0;k<8;++k)
                    acc8[k] += (word >> k) & 0x01010101u;
            }
        }
        int s = sBase + ls;
        #pragma unroll
        for (int k=0;k<8;++k)
            #pragma unroll
            for (int j=0;j<4;++j){
                int b = k + 8*j;
                cntT[(size_t)(w*32+b)*SNUM + s] = (unsigned char)((acc8[k] >> (8*j)) & 0xFF);
            }
    }
}

// ---------- 3. fused: top-10 per mask [0,800) + gated mean features [800,1824) ----------
__global__ __launch_bounds__(256) void k_topkfeats(const unsigned char* __restrict__ cntT,
                                                   const float* __restrict__ scores,
                                                   unsigned int* __restrict__ contrib,
                                                   float* __restrict__ wsum,
                                                   float* __restrict__ fsum,
                                                   const float* __restrict__ pf,
                                                   const unsigned int* __restrict__ needed,
                                                   float* __restrict__ feats){
    int bid = blockIdx.x;
    int t = threadIdx.x;
    if (bid < NMASK){
        int m = bid;
        __shared__ int hist[64];
        __shared__ int wsums[4];
        __shared__ int sT, sR;
        if (t < 64) hist[t]=0;
        __syncthreads();
        uchar4 c4 = ((const uchar4*)(cntT + (size_t)m*SNUM))[t];
        int c[4] = {(int)c4.x,(int)c4.y,(int)c4.z,(int)c4.w};
        atomicAdd(&hist[c[0]],1); atomicAdd(&hist[c[1]],1);
        atomicAdd(&hist[c[2]],1); atomicAdd(&hist[c[3]],1);
        __syncthreads();
        if (t==0){
            int running=0, T=0, r=10;
            for(int v=63;v>=0;--v){
                int nr = running + hist[v];
                if (nr >= 10){ T=v; r=10-running; break; }
                running = nr;
            }
            sT=T; sR=r;
        }
        __syncthreads();
        int T=sT, r=sR;
        int eq = (c[0]==T)+(c[1]==T)+(c[2]==T)+(c[3]==T);
        int incl = eq;
        #pragma unroll
        for (int off=1; off<64; off<<=1){
            int v = __shfl_up(incl, off);
            if ((t & 63) >= off) incl += v;
        }
        if ((t & 63) == 63) wsums[t>>6] = incl;
        __syncthreads();
        int base = 0;
        #pragma unroll
        for (int wv=0; wv<4; ++wv)
            if (wv < (t>>6)) base += wsums[wv];
        int rank = base + incl - eq;
        float sc = scores[m];
        #pragma unroll
        for(int j=0;j<4;++j){
            int s = t*4+j;
            bool selv = (c[j]>T) || (c[j]==T && rank<r);
            if (c[j]==T) rank++;
            if (selv && c[j]>0){
                float frac = (float)c[j]/60.0f;
                atomicAdd(&wsum[s], frac*sc);
                atomicAdd(&fsum[s], frac);
                if (c[j] >= 12)
                    atomicOr(&contrib[s*WORDS + (m>>5)], 1u<<(m&31));
            }
        }
    } else {
        int s = bid - NMASK;
        if (!needed[s]) return;
        int g = t >> 7;
        int c = t & 127;
        const float4* pf4 = (const float4*)pf;
        float4 a = make_float4(0.f,0.f,0.f,0.f);
        for (int p=g; p<PNUM; p+=2){
            float4 v = pf4[(size_t)(s*PNUM+p)*128 + c];
            a.x+=v.x; a.y+=v.y; a.z+=v.z; a.w+=v.w;
        }
        __shared__ float4 part[2][128];
        part[g][c] = a;
        __shared__ float red[256];
        __syncthreads();
        float4 m = make_float4(0.f,0.f,0.f,0.f);
        float ss = 0.f;
        if (g==0){
            float4 b = part[1][c];
            m.x=(a.x+b.x)/60.0f; m.y=(a.y+b.y)/60.0f; m.z=(a.z+b.z)/60.0f; m.w=(a.w+b.w)/60.0f;
            ss = m.x*m.x + m.y*m.y + m.z*m.z + m.w*m.w;
        }
        red[t] = ss; __syncthreads();
        for (int off=128; off; off>>=1){ if (t<off) red[t]+=red[t+off]; __syncthreads(); }
        float denom = fmaxf(sqrtf(red[0]), 1e-12f);
        if (g==0){
            float4 o; o.x=m.x/denom; o.y=m.y/denom; o.z=m.z/denom; o.w=m.w/denom;
            ((float4*)feats)[(size_t)s*128 + c] = o;
        }
    }
}

// ---------- 4. mod per edge + fused confidence ----------
__global__ __launch_bounds__(64) void k_mod(const unsigned int* __restrict__ ecnt,
                                            const unsigned int* __restrict__ edges,
                                            const unsigned int* __restrict__ contrib,
                                            const float* __restrict__ feats,
                                            const float* __restrict__ wsum,
                                            const float* __restrict__ fsum,
                                            float* __restrict__ conf,
                                            float* __restrict__ out){
    int lane = threadIdx.x;
    if (blockIdx.x < 16){
        int s = blockIdx.x*64 + lane;
        conf[s] = fmaxf(wsum[s]/(fsum[s]+1e-6f), 0.0f);
    }
    unsigned int n = *ecnt; if (n > EDGE_CAP) n = EDGE_CAP;
    for (unsigned int e = blockIdx.x; e < n; e += gridDim.x){
        unsigned int pk = edges[e];
        int i = (int)(pk>>10), j = (int)(pk & 1023u);
        const float4* fi = (const float4*)(feats + (size_t)i*FD);
        const float4* fj = (const float4*)(feats + (size_t)j*FD);
        float dot = 0.f;
        #pragma unroll
        for(int r=0;r<2;++r){
            float4 a = fi[lane + 64*r], b = fj[lane + 64*r];
            dot += a.x*b.x + a.y*b.y + a.z*b.z + a.w*b.w;
        }
        #pragma unroll
        for(int off=32;off;off>>=1) dot += __shfl_xor(dot,off);

        unsigned int u=0, aw=0; int cw=0;
        if (lane < WORDS){
            unsigned int bi = contrib[i*WORDS+lane], bj = contrib[j*WORDS+lane];
            u = bi|bj; aw = bi&bj; cw = __popc(u);
        }
        int pre=0, ctot=0;
        for(int k2=0;k2<WORDS;++k2){
            int v=__shfl(cw,k2);
            ctot += v;
            if (k2<lane) pre += v;
        }
        int il=0;
        if (lane<WORDS && pre<5){
            unsigned int x=u;
            int lim = 5-pre;
            #pragma unroll
            for(int q=0;q<5;++q){
                if (q<lim && x){
                    int b = __ffs(x)-1;
                    il += (int)((aw>>b)&1u);
                    x &= x-1;
                }
            }
        }
        #pragma unroll
        for(int off=32;off;off>>=1) il += __shfl_xor(il,off);
        int uni = min(ctot,5);
        float ov = (float)il / ((float)uni + 1e-6f);
        float sim = fminf(fmaxf((dot+1.0f)*0.5f,0.0f),1.0f);
        if (sim < 0.5f) sim = 1.0f;
        float mod = ov*sim;
        if (lane==0){
            size_t o = (size_t)i*SNUM+j;
            out[o] = fmaxf(out[o], mod);
        }
    }
}

extern "C" void kernel_launch(void* const* d_in, const int* in_sizes, int n_in,
                              void* d_out, int out_size, void* d_ws, size_t ws_size,
                              hipStream_t stream){
    const float*         pcds    = (const float*)d_in[0];
    const unsigned char* masks8  = (const unsigned char*)d_in[2];
    const int*           mapping = (const int*)d_in[3];
    const float*         scores  = (const float*)d_in[4];
    const float*         pf      = (const float*)d_in[5];
    float* out_adj  = (float*)d_out;
    float* out_conf = out_adj + (size_t)SNUM*SNUM;

    char* ws = (char*)d_ws;
    float*         reps    = (float*)(ws + 0);               // 122880 B
    unsigned int*  pb      = (unsigned int*)(ws + 131072);   // 6553600 B
    unsigned char* cntT    = (unsigned char*)(ws + 6684672); // 819200 B
    unsigned int*  contrib = (unsigned int*)(ws + 7503872);  // 102400 B  [zeroed in k_init]
    float*         wsum    = (float*)(ws + 7606272);         // 4096 B    [zeroed]
    float*         fsum    = (float*)(ws + 7610368);         // 4096 B    [zeroed]
    unsigned int*  needed  = (unsigned int*)(ws + 7614464);  // 4096 B    [zeroed]
    unsigned int*  ecnt    = (unsigned int*)(ws + 7618560);  // 4 B       [zeroed]
    unsigned int*  edges   = (unsigned int*)(ws + 7618568);  // 4 MB (cap 1M edges)
    float*         feats   = (float*)(ws + 11812880);        // 2 MB; total ~13.9 MB
    unsigned int*  zbase   = (unsigned int*)(ws + 7503872);  // 28673 words zero region

    k_init     <<<384, 512, 0, stream>>>(pcds, reps, zbase, masks8, pb);
    k_covadj   <<<NTILE + SNUM/8, 256, 0, stream>>>(reps, mapping, pb, cntT, out_adj, ecnt, edges, needed);
    k_topkfeats<<<NMASK + SNUM, 256, 0, stream>>>(cntT, scores, contrib, wsum, fsum, pf, needed, feats);
    k_mod      <<<1024, 64, 0, stream>>>(ecnt, edges, contrib, feats, wsum, fsum, out_conf, out_adj);
}